// Round 6
// baseline (382.226 us; speedup 1.0000x reference)
//
#include <hip/hip_runtime.h>

#define ALPHA_MIN 0.8187307530779818f  // exp(-1/5)
#define ALPHA_MAX 0.9607894391523232f  // exp(-1/25)

typedef _Float16 f16;
typedef _Float16 f16x8 __attribute__((ext_vector_type(8)));
typedef float f32x16 __attribute__((ext_vector_type(16)));

// Fixed problem shape (reference setup)
#define BB_ 32
#define TT_ 2048
#define KK_ 256
#define HH_ 512
#define TC_ 64               // timesteps per chunk
#define NSC 16               // superchunks (2 chunks each)
#define NB_ 64               // h-cols per block

// ============================ fused kernel ==================================
// grid = 256 = (nt<<5)|b : 8 n-panels of one batch land on one XCD (b%8) ->
// X[b] L2 reuse (verified: FETCH 35 MB).  block = 576 threads = 9 waves:
//   waves 0-7: GEMM, two groups (g=wv>>2). Group g computes chunk 2*sc+g of
//     superchunk sc -> 2 independent GEMM waves per SIMD (latency hiding).
//     Each wave: one 32x32 tile, fp16-split C = Ah*Bh + 2^-11(Ah*Bl+Al*Bh),
//     W-panel fragments in registers; k-loop has no LDS reads, no barrier.
//   wave  8 : LIF scan (64 h-chains) consumes superchunk sc-1 from LDS while
//     GEMM produces sc (4-buffer pipeline, one barrier per superchunk).
__global__ __launch_bounds__(576, 2) void lif_fused2(
    const float* __restrict__ X,      // (B,T,K)
    const float* __restrict__ W,      // (H,K)
    const float* __restrict__ alpha,  // (H)
    const float* __restrict__ u0,     // (B,H)
    const float* __restrict__ s0,     // (B,H)
    float* __restrict__ out)          // (B,T,H)
{
    __shared__ float wxbuf[4][TC_ * NB_];   // 4 x 16 KB

    const int b  = blockIdx.x & 31;
    const int nt = blockIdx.x >> 5;
    const int n0 = nt * NB_;

    const int tid  = threadIdx.x;
    const int wv   = tid >> 6;
    const int lane = tid & 63;
    const int fm   = lane & 31;
    const int fq   = lane >> 5;

    if (wv < 8) {
        // ------------------------- GEMM waves ------------------------------
        const int g  = wv >> 2;           // chunk group: handles chunks 2*sc+g
        const int mh = (wv >> 1) & 1;     // m-half within 64-row chunk
        const int nh = wv & 1;            // n-half within 64-col panel
        const int ncol = n0 + nh * 32 + fm;

        // B prologue: W[ncol][0..256) -> hi/lo f16 fragments in registers
        f16x8 bh[16], bl[16];
        {
            const float* wp = W + (size_t)ncol * KK_ + fq * 8;
#pragma unroll
            for (int ks = 0; ks < 16; ++ks) {
                float4 v0 = *(const float4*)(wp + ks * 16);
                float4 v1 = *(const float4*)(wp + ks * 16 + 4);
                float v[8] = {v0.x, v0.y, v0.z, v0.w, v1.x, v1.y, v1.z, v1.w};
                f16x8 h, l;
#pragma unroll
                for (int j = 0; j < 8; ++j) {
                    const f16 hj = (f16)v[j];
                    h[j] = hj;
                    l[j] = (f16)((v[j] - (float)hj) * 2048.0f);
                }
                bh[ks] = h; bl[ks] = l;
            }
        }

        f32x16 accH, accL;
#pragma unroll
        for (int e = 0; e < 16; ++e) { accH[e] = 0.0f; accL[e] = 0.0f; }

        // A row for this lane in chunk 2*sc+g: t = (2*sc+g)*64 + mh*32 + fm
        const float* xrow = X + ((size_t)b * TT_ + g * TC_ + mh * 32 + fm) * KK_ + fq * 8;

        // rolling 8-deep prefetch over flat k-index ki = sc*16 + ks
        float4 abuf[8][2];
        auto pref = [&](int ki) {
            if (ki < NSC * 16) {
                const float* p = xrow + (size_t)(ki >> 4) * (2 * TC_ * KK_) + (ki & 15) * 16;
                abuf[ki & 7][0] = *(const float4*)p;
                abuf[ki & 7][1] = *(const float4*)(p + 4);
            }
        };
#pragma unroll
        for (int i = 0; i < 8; ++i) pref(i);

        for (int sc = 0; sc < NSC; ++sc) {
            int ki = sc * 16;
#pragma unroll
            for (int ks = 0; ks < 16; ++ks, ++ki) {
                const float4 a0 = abuf[ki & 7][0];
                const float4 a1 = abuf[ki & 7][1];
                pref(ki + 8);
                const float v[8] = {a0.x, a0.y, a0.z, a0.w, a1.x, a1.y, a1.z, a1.w};
                f16x8 ah, al;
#pragma unroll
                for (int j = 0; j < 8; ++j) {
                    const f16 hj = (f16)v[j];
                    ah[j] = hj;
                    al[j] = (f16)((v[j] - (float)hj) * 2048.0f);
                }
                accH = __builtin_amdgcn_mfma_f32_32x32x16_f16(ah, bh[ks], accH, 0, 0, 0);
                accL = __builtin_amdgcn_mfma_f32_32x32x16_f16(ah, bl[ks], accL, 0, 0, 0);
                accL = __builtin_amdgcn_mfma_f32_32x32x16_f16(al, bh[ks], accL, 0, 0, 0);
            }
            // epilogue: 32x32 tile -> wxbuf[(sc&1)*2 + g]
            // C/D layout: col = lane&31, row = (r&3) + 8*(r>>2) + 4*(lane>>5)
            float* wb = &wxbuf[(sc & 1) * 2 + g][0];
#pragma unroll
            for (int r = 0; r < 16; ++r) {
                const int row = mh * 32 + (r & 3) + 8 * (r >> 2) + 4 * fq;
                wb[row * NB_ + nh * 32 + fm] = accH[r] + accL[r] * (1.0f / 2048.0f);
                accH[r] = 0.0f; accL[r] = 0.0f;
            }
            __syncthreads();
        }
    } else {
        // ------------------------- scan wave (wv==8) -----------------------
        const int h = n0 + lane;
        const int chain = b * HH_ + h;
        float a = alpha[h];
        a = fminf(fmaxf(a, ALPHA_MIN), ALPHA_MAX);
        const float bbv = 1.0f - a;
        float u = u0[chain];
        float s = s0[chain];
        float* op = out + (size_t)b * TT_ * HH_ + h;

        auto consume_pair = [&](int p) {
#pragma unroll
            for (int half = 0; half < 2; ++half) {
                const float* wb = &wxbuf[(p & 1) * 2 + half][0];
                const int tbase = (2 * p + half) * TC_;
                for (int t0 = 0; t0 < TC_; t0 += 8) {
                    float w[8];
#pragma unroll
                    for (int j = 0; j < 8; ++j) w[j] = wb[(t0 + j) * NB_ + lane];
#pragma unroll
                    for (int j = 0; j < 8; ++j) {
                        u = fmaf(a, u - s, bbv * w[j]);
                        s = (u > 1.0f) ? 1.0f : 0.0f;
                        __builtin_nontemporal_store(s, &op[(size_t)(tbase + t0 + j) * HH_]);
                    }
                }
            }
        };

        for (int sc = 0; sc < NSC; ++sc) {
            if (sc > 0) consume_pair(sc - 1);
            __syncthreads();
        }
        consume_pair(NSC - 1);
    }
}

// =================== generic fallback (never hit for ref shape) =============
__global__ void gemm_naive(const float* __restrict__ X, const float* __restrict__ W,
                           float* __restrict__ C, int M, int N, int K)
{
    const int idx = blockIdx.x * 256 + threadIdx.x;
    if (idx >= M * N) return;
    const int m = idx / N, n = idx % N;
    float acc = 0.0f;
    for (int k = 0; k < K; ++k) acc = fmaf(X[(size_t)m * K + k], W[(size_t)n * K + k], acc);
    C[idx] = acc;
}

__global__ __launch_bounds__(64) void lif_scan_inplace(
    float* __restrict__ buf, const float* __restrict__ alpha,
    const float* __restrict__ u0, const float* __restrict__ s0, int T, int H)
{
    const int chain = blockIdx.x * 64 + threadIdx.x;
    const int h = chain % H;
    const int b = chain / H;
    float a = alpha[h];
    a = fminf(fmaxf(a, ALPHA_MIN), ALPHA_MAX);
    const float bb = 1.0f - a;
    float u = u0[chain], s = s0[chain];
    float* base = buf + (size_t)b * T * H + h;
    for (int t = 0; t < T; ++t) {
        u = fmaf(a, u - s, bb * base[(size_t)t * H]);
        s = (u > 1.0f) ? 1.0f : 0.0f;
        base[(size_t)t * H] = s;
    }
}

// ---------------- launch ----------------------------------------------------
extern "C" void kernel_launch(void* const* d_in, const int* in_sizes, int n_in,
                              void* d_out, int out_size, void* d_ws, size_t ws_size,
                              hipStream_t stream) {
    const float* x     = (const float*)d_in[0];
    const float* W     = (const float*)d_in[1];
    const float* alpha = (const float*)d_in[2];
    const float* u0    = (const float*)d_in[3];
    const float* s0    = (const float*)d_in[4];
    float* out = (float*)d_out;

    const int H = in_sizes[2];
    const int I = in_sizes[1] / H;
    const int B = in_sizes[3] / H;
    const int T = in_sizes[0] / (B * I);

    if (B == BB_ && T == TT_ && I == KK_ && H == HH_) {
        lif_fused2<<<256, 576, 0, stream>>>(x, W, alpha, u0, s0, out);
    } else {
        const int M = B * T;
        gemm_naive<<<(M * H + 255) / 256, 256, 0, stream>>>(x, W, out, M, H, I);
        lif_scan_inplace<<<(B * H + 63) / 64, 64, 0, stream>>>(out, alpha, u0, s0, T, H);
    }
}

// Round 7
// 329.291 us; speedup vs baseline: 1.1608x; 1.1608x over previous
//
#include <hip/hip_runtime.h>

#define ALPHA_MIN 0.8187307530779818f  // exp(-1/5)
#define ALPHA_MAX 0.9607894391523232f  // exp(-1/25)

typedef _Float16 f16;
typedef _Float16 f16x8 __attribute__((ext_vector_type(8)));
typedef float f32x16 __attribute__((ext_vector_type(16)));

// Fixed problem shape (reference setup)
#define BB_ 32
#define TT_ 2048
#define KK_ 256
#define HH_ 512
#define TC_ 64               // timesteps per chunk
#define NSC 16               // superchunks of 2 chunks
#define NB_ 64               // h-cols per block

// ============================ fused kernel ==================================
// grid = 256 = (nt<<5)|b : 8 n-panels of batch b land on XCD b%8 -> X[b] L2
// reuse (verified R5: FETCH 35 MB, 0 bank conflicts).
// block = 320 threads = 5 waves, launch_bounds(320,1) -> ~512-reg budget,
// B-panel fragments (128 VGPR) + 2 acc pairs (64 AGPR) + 2 A-streams fit
// WITHOUT spilling (R6 post-mortem: 2-blocks/CU bound caused spill storm).
//   waves 0-3: GEMM. Each wave owns one 32x32 tile position and processes
//     TWO chunks (2*sc, 2*sc+1) concurrently: two independent MFMA chains
//     interleaved -> fills the 1-wave/SIMD latency bubbles. fp16-split:
//     C = Ah*Bh + 2^-11*(Ah*Bl + Al*Bh); k-loop has no LDS, no barrier.
//   wave  4 : LIF scan (64 h-chains) consumes superchunk sc-1 from LDS while
//     GEMM produces sc (4 x 16 KB buffers, one barrier per superchunk).
__global__ __launch_bounds__(320, 1) void lif_fused3(
    const float* __restrict__ X,      // (B,T,K)
    const float* __restrict__ W,      // (H,K)
    const float* __restrict__ alpha,  // (H)
    const float* __restrict__ u0,     // (B,H)
    const float* __restrict__ s0,     // (B,H)
    float* __restrict__ out)          // (B,T,H)
{
    __shared__ float wxbuf[4][TC_ * NB_];   // 4 x 16 KB

    const int b  = blockIdx.x & 31;
    const int nt = blockIdx.x >> 5;
    const int n0 = nt * NB_;

    const int tid  = threadIdx.x;
    const int wv   = tid >> 6;
    const int lane = tid & 63;
    const int fm   = lane & 31;
    const int fq   = lane >> 5;

    if (wv < 4) {
        // ------------------------- GEMM waves ------------------------------
        const int mh = wv >> 1;           // m-half within 64-row chunk
        const int nh = wv & 1;            // n-half within 64-col panel
        const int ncol = n0 + nh * 32 + fm;

        // B prologue: W[ncol][0..256) -> hi/lo f16 fragments (128 VGPRs)
        f16x8 bh[16], bl[16];
        {
            const float* wp = W + (size_t)ncol * KK_ + fq * 8;
#pragma unroll
            for (int ks = 0; ks < 16; ++ks) {
                float4 v0 = *(const float4*)(wp + ks * 16);
                float4 v1 = *(const float4*)(wp + ks * 16 + 4);
                float v[8] = {v0.x, v0.y, v0.z, v0.w, v1.x, v1.y, v1.z, v1.w};
                f16x8 h, l;
#pragma unroll
                for (int j = 0; j < 8; ++j) {
                    const f16 hj = (f16)v[j];
                    h[j] = hj;
                    l[j] = (f16)((v[j] - (float)hj) * 2048.0f);
                }
                bh[ks] = h; bl[ks] = l;
            }
        }

        f32x16 accH[2], accL[2];
#pragma unroll
        for (int p = 0; p < 2; ++p)
#pragma unroll
            for (int e = 0; e < 16; ++e) { accH[p][e] = 0.0f; accL[p][e] = 0.0f; }

        // A row pointers, stream p covers chunk 2*sc+p; lane row = mh*32+fm
        const float* xrow[2];
        xrow[0] = X + ((size_t)b * TT_ + 0 * TC_ + mh * 32 + fm) * KK_ + fq * 8;
        xrow[1] = X + ((size_t)b * TT_ + 1 * TC_ + mh * 32 + fm) * KK_ + fq * 8;

        // rolling 4-deep prefetch per stream over flat ki = sc*16 + ks
        float4 abuf[2][4][2];
#pragma unroll
        for (int p = 0; p < 2; ++p)
#pragma unroll
            for (int i = 0; i < 4; ++i) {
                const float* q = xrow[p] + (size_t)(i >> 4) * (2 * TC_ * KK_) + (i & 15) * 16;
                abuf[p][i][0] = *(const float4*)q;
                abuf[p][i][1] = *(const float4*)(q + 4);
            }

        for (int sc = 0; sc < NSC; ++sc) {
#pragma unroll
            for (int ks = 0; ks < 16; ++ks) {
                f16x8 ah[2], al[2];
#pragma unroll
                for (int p = 0; p < 2; ++p) {
                    const float4 a0 = abuf[p][ks & 3][0];
                    const float4 a1 = abuf[p][ks & 3][1];
                    // prefetch ki+4 into the slot just freed
                    const int nki = sc * 16 + ks + 4;
                    if (nki < NSC * 16) {
                        const float* q = xrow[p] + (size_t)(nki >> 4) * (2 * TC_ * KK_)
                                       + (nki & 15) * 16;
                        abuf[p][ks & 3][0] = *(const float4*)q;
                        abuf[p][ks & 3][1] = *(const float4*)(q + 4);
                    }
                    const float v[8] = {a0.x, a0.y, a0.z, a0.w, a1.x, a1.y, a1.z, a1.w};
                    f16x8 h, l;
#pragma unroll
                    for (int j = 0; j < 8; ++j) {
                        const f16 hj = (f16)v[j];
                        h[j] = hj;
                        l[j] = (f16)((v[j] - (float)hj) * 2048.0f);
                    }
                    ah[p] = h; al[p] = l;
                }
                // interleaved MFMAs: 6 per ks, 2 independent chain pairs
                accH[0] = __builtin_amdgcn_mfma_f32_32x32x16_f16(ah[0], bh[ks], accH[0], 0, 0, 0);
                accH[1] = __builtin_amdgcn_mfma_f32_32x32x16_f16(ah[1], bh[ks], accH[1], 0, 0, 0);
                accL[0] = __builtin_amdgcn_mfma_f32_32x32x16_f16(ah[0], bl[ks], accL[0], 0, 0, 0);
                accL[1] = __builtin_amdgcn_mfma_f32_32x32x16_f16(ah[1], bl[ks], accL[1], 0, 0, 0);
                accL[0] = __builtin_amdgcn_mfma_f32_32x32x16_f16(al[0], bh[ks], accL[0], 0, 0, 0);
                accL[1] = __builtin_amdgcn_mfma_f32_32x32x16_f16(al[1], bh[ks], accL[1], 0, 0, 0);
            }

            // epilogue: both 32x32 tiles -> wxbuf[(sc&1)*2 + p]
            // C/D layout: col = lane&31, row = (r&3) + 8*(r>>2) + 4*(lane>>5)
#pragma unroll
            for (int p = 0; p < 2; ++p) {
                float* wb = &wxbuf[(sc & 1) * 2 + p][0];
#pragma unroll
                for (int r = 0; r < 16; ++r) {
                    const int row = mh * 32 + (r & 3) + 8 * (r >> 2) + 4 * fq;
                    wb[row * NB_ + nh * 32 + fm] = accH[p][r] + accL[p][r] * (1.0f / 2048.0f);
                    accH[p][r] = 0.0f; accL[p][r] = 0.0f;
                }
            }
            // advance A pointers by one superchunk (2 chunks) handled via ki
            __syncthreads();
        }
    } else {
        // ------------------------- scan wave (wv==4) -----------------------
        const int h = n0 + lane;
        const int chain = b * HH_ + h;
        float a = alpha[h];
        a = fminf(fmaxf(a, ALPHA_MIN), ALPHA_MAX);
        const float bbv = 1.0f - a;
        float u = u0[chain];
        float s = s0[chain];
        float* op = out + (size_t)b * TT_ * HH_ + h;

        auto consume_pair = [&](int p) {
#pragma unroll
            for (int half = 0; half < 2; ++half) {
                const float* wb = &wxbuf[(p & 1) * 2 + half][0];
                const int tbase = (2 * p + half) * TC_;
                for (int t0 = 0; t0 < TC_; t0 += 8) {
                    float w[8];
#pragma unroll
                    for (int j = 0; j < 8; ++j) w[j] = wb[(t0 + j) * NB_ + lane];
#pragma unroll
                    for (int j = 0; j < 8; ++j) {
                        u = fmaf(a, u - s, bbv * w[j]);
                        s = (u > 1.0f) ? 1.0f : 0.0f;
                        __builtin_nontemporal_store(s, &op[(size_t)(tbase + t0 + j) * HH_]);
                    }
                }
            }
        };

        for (int sc = 0; sc < NSC; ++sc) {
            if (sc > 0) consume_pair(sc - 1);
            __syncthreads();
        }
        consume_pair(NSC - 1);
    }
}

// =================== generic fallback (never hit for ref shape) =============
__global__ void gemm_naive(const float* __restrict__ X, const float* __restrict__ W,
                           float* __restrict__ C, int M, int N, int K)
{
    const int idx = blockIdx.x * 256 + threadIdx.x;
    if (idx >= M * N) return;
    const int m = idx / N, n = idx % N;
    float acc = 0.0f;
    for (int k = 0; k < K; ++k) acc = fmaf(X[(size_t)m * K + k], W[(size_t)n * K + k], acc);
    C[idx] = acc;
}

__global__ __launch_bounds__(64) void lif_scan_inplace(
    float* __restrict__ buf, const float* __restrict__ alpha,
    const float* __restrict__ u0, const float* __restrict__ s0, int T, int H)
{
    const int chain = blockIdx.x * 64 + threadIdx.x;
    const int h = chain % H;
    const int b = chain / H;
    float a = alpha[h];
    a = fminf(fmaxf(a, ALPHA_MIN), ALPHA_MAX);
    const float bb = 1.0f - a;
    float u = u0[chain], s = s0[chain];
    float* base = buf + (size_t)b * T * H + h;
    for (int t = 0; t < T; ++t) {
        u = fmaf(a, u - s, bb * base[(size_t)t * H]);
        s = (u > 1.0f) ? 1.0f : 0.0f;
        base[(size_t)t * H] = s;
    }
}

// ---------------- launch ----------------------------------------------------
extern "C" void kernel_launch(void* const* d_in, const int* in_sizes, int n_in,
                              void* d_out, int out_size, void* d_ws, size_t ws_size,
                              hipStream_t stream) {
    const float* x     = (const float*)d_in[0];
    const float* W     = (const float*)d_in[1];
    const float* alpha = (const float*)d_in[2];
    const float* u0    = (const float*)d_in[3];
    const float* s0    = (const float*)d_in[4];
    float* out = (float*)d_out;

    const int H = in_sizes[2];
    const int I = in_sizes[1] / H;
    const int B = in_sizes[3] / H;
    const int T = in_sizes[0] / (B * I);

    if (B == BB_ && T == TT_ && I == KK_ && H == HH_) {
        lif_fused3<<<256, 320, 0, stream>>>(x, W, alpha, u0, s0, out);
    } else {
        const int M = B * T;
        gemm_naive<<<(M * H + 255) / 256, 256, 0, stream>>>(x, W, out, M, H, I);
        lif_scan_inplace<<<(B * H + 63) / 64, 64, 0, stream>>>(out, alpha, u0, s0, T, H);
    }
}